// Round 25
// baseline (164.299 us; speedup 1.0000x reference)
//
#include <hip/hip_runtime.h>
#include <hip/hip_bf16.h>
#include <hip/hip_cooperative_groups.h>

#define NB 64
#define NN 512
#define CI 32
#define CO 64
#define XN 68
// Ybf layout: [b][kb=0..15][row=0..79][32], bf16, pre-scaled by c0/n.
// Abf (fallback only): [b][ic=0..7][c=0..7][4096], bf16(A), fragment-linear XOR-swizzled.

typedef __attribute__((ext_vector_type(8))) short bf16x8;
typedef __attribute__((ext_vector_type(4))) float f32x4;

__device__ inline short f2bf(float f) {
  union { __hip_bfloat16 h; unsigned short u; } cv;
  cv.h = __float2bfloat16(f);
  return (short)cv.u;
}
__device__ inline float bf2f(unsigned short u) {
  union { unsigned int i; float f; } c;
  c.i = ((unsigned int)u) << 16;
  return c.f;
}
__device__ inline bf16x8 cvt8(float4 a, float4 b) {
  bf16x8 r;
  r[0] = f2bf(a.x); r[1] = f2bf(a.y); r[2] = f2bf(a.z); r[3] = f2bf(a.w);
  r[4] = f2bf(b.x); r[5] = f2bf(b.y); r[6] = f2bf(b.z); r[7] = f2bf(b.w);
  return r;
}
__device__ inline void astore8(unsigned short* p, unsigned long long v) {
  __hip_atomic_store((unsigned long long*)p, v, __ATOMIC_RELAXED,
                     __HIP_MEMORY_SCOPE_AGENT);
}
__device__ inline void astoref(float* p, float v) {
  __hip_atomic_store(p, v, __ATOMIC_RELAXED, __HIP_MEMORY_SCOPE_AGENT);
}
__device__ inline float aloadf(const float* p) {
  return __hip_atomic_load((float*)p, __ATOMIC_RELAXED, __HIP_MEMORY_SCOPE_AGENT);
}
__device__ inline bf16x8 aload16(const unsigned short* p) {
  union { unsigned long long q[2]; bf16x8 v; } u;
  u.q[0] = __hip_atomic_load((unsigned long long*)p, __ATOMIC_RELAXED,
                             __HIP_MEMORY_SCOPE_AGENT);
  u.q[1] = __hip_atomic_load((unsigned long long*)p + 1, __ATOMIC_RELAXED,
                             __HIP_MEMORY_SCOPE_AGENT);
  return u.v;
}

// ================= KMAIN: single-pass cooperative. grid (4, NB), 512 thr, 1 blk/CU =================
__global__ __launch_bounds__(512, 2) void kmain(
    const float* __restrict__ A, const float* __restrict__ X,
    const float* __restrict__ cf, const float* __restrict__ W1,
    const float* __restrict__ W2,
    float* __restrict__ pA, float* __restrict__ pD, float* __restrict__ pS,
    float* __restrict__ pmX, float* __restrict__ ptC,
    unsigned short* __restrict__ Ybf, float* __restrict__ out) {
  int ic = blockIdx.x, b = blockIdx.y;
  int t = threadIdx.x, w = t >> 6, lane = t & 63;
  int i0 = ic * 128;

  __shared__ unsigned short sA[8 * 128 * 64];   // 128KB bf16 A-tile, XOR-swizzled slots
  __shared__ unsigned short sXfh[128][32];      // 8KB bf16 X rows
  __shared__ float sMc[128], sDg[128], sVec[128], sRs[128];
  __shared__ float sColv[64 * 8];
  __shared__ float scf[72];
  __shared__ float sStat[8];     // 0 md, 1 ma, 2 sconst, 3 ssum, 4 ssmc, 5 ssdg
  __shared__ float sMXs[32], sTCs[32];

  if (t < 69) scf[t] = cf[t];

  // ---- phase 1a: stream A once (rowsum, diag, bf16 LDS tile); stage X bf16 ----
  int r = t >> 2, s = t & 3;
  int row_g = i0 + r;
  const float* Arow = A + ((size_t)(b * NN) + row_g) * NN;
  {
    const float* xp = X + ((size_t)(b * NN) + row_g) * CI + s * 8;
    float4 x0 = *(const float4*)xp, x1 = *(const float4*)(xp + 4);
    *(bf16x8*)&sXfh[r][s * 8] = cvt8(x0, x1);
  }
  float rowsum = 0.f;
  int s_d = row_g >> 7, g_d = (row_g & 127) >> 4, e_d = row_g & 15;
#pragma unroll
  for (int g8 = 0; g8 < 8; ++g8) {
    int col = s * 128 + g8 * 16;
    float4 a0 = *(const float4*)(Arow + col);
    float4 a1 = *(const float4*)(Arow + col + 4);
    float4 a2 = *(const float4*)(Arow + col + 8);
    float4 a3 = *(const float4*)(Arow + col + 12);
    rowsum += (a0.x + a0.y) + (a0.z + a0.w) + (a1.x + a1.y) + (a1.z + a1.w) +
              (a2.x + a2.y) + (a2.z + a2.w) + (a3.x + a3.y) + (a3.z + a3.w);
    if (s == s_d && g8 == g_d) {
      int q = e_d >> 2, e = e_d & 3;
      float4 pick = (q == 0) ? a0 : (q == 1) ? a1 : (q == 2) ? a2 : a3;
      sDg[r] = (&pick.x)[e];
    }
    int c64 = col >> 6, c0 = col & 63;
    int sl0 = c0 >> 3;
    int base = (c64 * 128 + r) * 64;
    *(bf16x8*)&sA[base + ((sl0 ^ (r & 7)) << 3)] = cvt8(a0, a1);
    *(bf16x8*)&sA[base + (((sl0 + 1) ^ (r & 7)) << 3)] = cvt8(a2, a3);
  }
  rowsum += __shfl_xor(rowsum, 1, 64);
  rowsum += __shfl_xor(rowsum, 2, 64);
  if (s == 0) {
    sRs[r] = rowsum;
    sMc[r] = rowsum * (1.0f / NN);
  }
  __syncthreads();  // sA, sXfh, sMc, sDg, sRs, scf ready

  float c0n = scf[0] * (1.0f / NN);

  // ---- phase 1b: vec per row ----
  if (t < 128) {
    float u = 0.f;
#pragma unroll
    for (int c = 0; c < CI; ++c) u += scf[5 + c] * bf2f(sXfh[t][c]);
    sVec[t] = scf[3] * sMc[t] + scf[4] * sDg[t] + u;
  }
  __syncthreads();  // sVec ready

  // ---- phase 1c: Y production (this block's 128 j-cols); Ybf rows 64/65; pads; partials ----
  {
    int ra = lane & 15, kg = lane >> 4, g = lane >> 4;
    int j0 = w * 16;
    bf16x8 xf = *(const bf16x8*)&sXfh[j0 + ra][kg * 8];
#pragma unroll
    for (int to = 0; to < 4; ++to) {
      const float* wp = W1 + (to * 16 + ra) * XN + kg * 8;
      bf16x8 wf = cvt8(*(const float4*)wp, *(const float4*)(wp + 4));
      f32x4 zero = {0.f, 0.f, 0.f, 0.f};
      f32x4 d = __builtin_amdgcn_mfma_f32_16x16x32_bf16(xf, wf, zero, 0, 0, 0);
      int o = to * 16 + ra;
      int jg = i0 + j0 + g * 4;
      int kb = jg >> 5, colj = jg & 31;
      union { unsigned short u4[4]; unsigned long long q; } pk;
#pragma unroll
      for (int rr = 0; rr < 4; ++rr) pk.u4[rr] = (unsigned short)f2bf(d[rr] * c0n);
      astore8(&Ybf[(((size_t)b * 16 + kb) * 80 + o) * 32 + colj], pk.q);
    }
  }
  if (t < 64) {  // rows 64 (c0n*mc), 65 (c0n*dg): 8B packs over the block's 128 cols
    int isdg = t >> 5, p = t & 31;
    int jg = i0 + p * 4;
    int kb = jg >> 5, colj = jg & 31;
    union { unsigned short u4[4]; unsigned long long q; } pk;
#pragma unroll
    for (int k = 0; k < 4; ++k) {
      float v = (isdg ? sDg[p * 4 + k] : sMc[p * 4 + k]) * c0n;
      pk.u4[k] = (unsigned short)f2bf(v);
    }
    astore8(&Ybf[(((size_t)b * 16 + kb) * 80 + 64 + isdg) * 32 + colj], pk.q);
  }
  if (t < 448) {  // zero pad rows 66..79 of this block's 4 kb panels
    int kb_i = t / 112, rem = t % 112;
    int rr = 66 + rem / 8, c8 = (rem % 8) * 4;
    astore8(&Ybf[(((size_t)b * 16 + 4 * ic + kb_i) * 80 + rr) * 32 + c8], 0ULL);
  }
  if (t < 32) {  // column partials over the block's 128 rows
    float s1 = 0.f, s2 = 0.f;
    for (int rr = 0; rr < 128; ++rr) {
      float xvv = bf2f(sXfh[rr][t]);
      s1 += xvv;
      s2 += sVec[rr] * xvv;
    }
    astoref(&pmX[((size_t)b * 4 + ic) * 32 + t], s1);
    astoref(&ptC[((size_t)b * 4 + ic) * 32 + t], s2);
  } else if (t == 32) {
    float sa = 0.f, sd = 0.f;
    for (int rr = 0; rr < 128; ++rr) { sa += sRs[rr]; sd += sDg[rr]; }
    astoref(&pA[b * 4 + ic], sa);
    astoref(&pD[b * 4 + ic], sd);
  } else if (t < 36) {
    int k = t - 33;
    float ss = 0.f;
    if (k == 0) for (int rr = 0; rr < 128; ++rr) ss += sVec[rr];
    if (k == 1) for (int rr = 0; rr < 128; ++rr) ss += sVec[rr] * sMc[rr];
    if (k == 2) for (int rr = 0; rr < 128; ++rr) ss += sVec[rr] * sDg[rr];
    astoref(&pS[((size_t)b * 4 + ic) * 3 + k], ss);
  }

  __threadfence();
  cooperative_groups::this_grid().sync();
  __threadfence();

  // ---- phase 1.5: reduce partials -> colv, sconst (per-block redundant) ----
  if (t < 32) {
    float s1 = 0.f, s2 = 0.f;
#pragma unroll
    for (int k = 0; k < 4; ++k) {
      s1 += aloadf(&pmX[((size_t)b * 4 + k) * 32 + t]);
      s2 += aloadf(&ptC[((size_t)b * 4 + k) * 32 + t]);
    }
    sMXs[t] = s1 * (1.0f / NN);
    sTCs[t] = s2;
  } else if (t == 32) {
    float sa = 0.f, sd = 0.f;
#pragma unroll
    for (int k = 0; k < 4; ++k) {
      sa += aloadf(&pA[b * 4 + k]);
      sd += aloadf(&pD[b * 4 + k]);
    }
    sStat[1] = sa * (1.0f / ((float)NN * (float)NN));
    sStat[0] = sd * (1.0f / NN);
  } else if (t == 33) {
    float s1 = 0.f, s2 = 0.f, s3 = 0.f;
#pragma unroll
    for (int k = 0; k < 4; ++k) {
      s1 += aloadf(&pS[((size_t)b * 4 + k) * 3 + 0]);
      s2 += aloadf(&pS[((size_t)b * 4 + k) * 3 + 1]);
      s3 += aloadf(&pS[((size_t)b * 4 + k) * 3 + 2]);
    }
    sStat[3] = s1; sStat[4] = s2; sStat[5] = s3;
  }
  __syncthreads();
  if (t == 0) {
    float s7 = 0.f;
#pragma unroll
    for (int c = 0; c < CI; ++c) s7 += scf[5 + CI + c] * sMXs[c];
    sStat[2] = scf[1] * sStat[1] + scf[2] * sStat[0] + s7;
  }
  if (t < CO) {
    int o = t;
    const float* w1 = W1 + o * XN;
    const float* w2 = W2 + o * XN;
    float w1mX = 0.f, a1 = 0.f, a2 = 0.f, wt = 0.f;
#pragma unroll
    for (int c = 0; c < CI; ++c) {
      float m = sMXs[c];
      w1mX += w1[c] * m;
      a1 += w1[CI + c] * m;
      a2 += w2[CI + c] * m;
      wt += w1[c] * sTCs[c];
    }
    float smd = sStat[0], sma = sStat[1];
    a1 += w1[66] * smd + w1[67] * sma;
    a2 += w2[66] * smd + w2[67] * sma;
    float we0 = w1[64], we1 = w1[65];
    float S1n = w1mX + a1 + we0 * sma + we1 * smd;
    float SVn = (wt + a1 * sStat[3] + we0 * sStat[4] + we1 * sStat[5]) * (1.0f / NN);
    sColv[o * 8 + 0] = S1n;
    sColv[o * 8 + 1] = a2 + SVn;
    sColv[o * 8 + 2] = w2[64] + scf[0] * a1;
    sColv[o * 8 + 3] = w2[65];
    sColv[o * 8 + 4] = we0;
    sColv[o * 8 + 5] = we1;
  }
  __syncthreads();

  // ---- phase 2: GEMM, A from LDS, B via agent loads (MALL) ----
  {
    int ra = lane & 15, kg = lane >> 4, g = lane >> 4;
    int wr0 = w * 16;
    int rr_ = wr0 + ra;
    const unsigned short* Yb = Ybf + (size_t)b * 16 * 2560;

    f32x4 acc[4] = {{0.f, 0.f, 0.f, 0.f}, {0.f, 0.f, 0.f, 0.f},
                    {0.f, 0.f, 0.f, 0.f}, {0.f, 0.f, 0.f, 0.f}};
    f32x4 acc4 = {0.f, 0.f, 0.f, 0.f};

#pragma unroll
    for (int jj = 0; jj < 16; ++jj) {
      int c64 = jj >> 1, kbl = jj & 1;
      bf16x8 af = *(const bf16x8*)&sA[(c64 * 128 + rr_) * 64 +
                                      (((kbl * 4 + kg) ^ (rr_ & 7)) << 3)];
      const unsigned short* Bb = Yb + (size_t)jj * 2560;
#pragma unroll
      for (int to = 0; to < 4; ++to) {
        bf16x8 bf = aload16(&Bb[(to * 16 + ra) * 32 + kg * 8]);
        acc[to] = __builtin_amdgcn_mfma_f32_16x16x32_bf16(af, bf, acc[to], 0, 0, 0);
      }
      bf16x8 b4 = aload16(&Bb[(64 + ra) * 32 + kg * 8]);
      acc4 = __builtin_amdgcn_mfma_f32_16x16x32_bf16(af, b4, acc4, 0, 0, 0);
    }

    {  // fused X*W2c k-step (unscaled), X bf16 from LDS
      bf16x8 xf2 = *(const bf16x8*)&sXfh[rr_][kg * 8];
#pragma unroll
      for (int to = 0; to < 4; ++to) {
        const float* wp = W2 + (size_t)(to * 16 + ra) * XN + kg * 8;
        bf16x8 wf = cvt8(*(const float4*)wp, *(const float4*)(wp + 4));
        acc[to] = __builtin_amdgcn_mfma_f32_16x16x32_bf16(xf2, wf, acc[to], 0, 0, 0);
      }
    }

    float Gm[4], Gd[4];
#pragma unroll
    for (int rr = 0; rr < 4; ++rr) {
      Gm[rr] = __shfl(acc4[rr], lane & 48, 64);
      Gd[rr] = __shfl(acc4[rr], (lane & 48) | 1, 64);
    }

    float sc = sStat[2];
    float vp[4], mr[4], dr[4];
#pragma unroll
    for (int rr = 0; rr < 4; ++rr) {
      int row = wr0 + g * 4 + rr;
      vp[rr] = sVec[row] + sc;
      mr[rr] = sMc[row];
      dr[rr] = sDg[row];
    }

#pragma unroll
    for (int to = 0; to < 4; ++to) {
      int o = to * 16 + ra;
      float4 cva = *(const float4*)&sColv[o * 8];
      float vb0 = sColv[o * 8 + 4], vb1 = sColv[o * 8 + 5];
#pragma unroll
      for (int rr = 0; rr < 4; ++rr) {
        float val = acc[to][rr] + vp[rr] * cva.x + cva.y + mr[rr] * cva.z +
                    dr[rr] * cva.w + Gm[rr] * vb0 + Gd[rr] * vb1;
        out[((size_t)(b * NN + i0 + wr0 + g * 4 + rr)) * CO + o] = val;
      }
    }
  }
}

// ================= FALLBACK PATH (R24, passing at 45.9 µs) =================
__global__ __launch_bounds__(256) void k1x(
    const float* __restrict__ A, const float* __restrict__ X,
    const float* __restrict__ cf, const float* __restrict__ W1,
    float* __restrict__ mc, float* __restrict__ dg, float* __restrict__ vec,
    float* __restrict__ pA, float* __restrict__ pD,
    float* __restrict__ pmX, float* __restrict__ ptC, float* __restrict__ pS,
    unsigned short* __restrict__ Ybf, unsigned short* __restrict__ Abf) {
  int b = blockIdx.x, ch = blockIdx.y;
  int t = threadIdx.x, w = t >> 6, lane = t & 63;
  int r0 = ch * 16;
  int kb = r0 >> 5, jbase = r0 & 16;
  const float* Ab = A + (size_t)b * NN * NN;
  __shared__ float sXc[16][33];
  __shared__ float scf[69];
  __shared__ float sMc[16], sDg[16], sVec[16], wsum[4];

  if (t < 69) scf[t] = cf[t];
  {
    int j = t >> 4, c = (t & 15) * 2;
    float2 xv = *(const float2*)(X + ((size_t)b * NN + r0 + j) * CI + c);
    sXc[j][c] = xv.x; sXc[j][c + 1] = xv.y;
  }
  float4 v0[4], v1[4];
#pragma unroll
  for (int m = 0; m < 4; ++m) {
    const float* rp = Ab + (size_t)(r0 + w * 4 + m) * NN;
    v0[m] = *(const float4*)(rp + lane * 4);
    v1[m] = *(const float4*)(rp + 256 + lane * 4);
  }
  float accR = 0.f;
#pragma unroll
  for (int m = 0; m < 4; ++m) {
    float s = (v0[m].x + v0[m].y) + (v0[m].z + v0[m].w) +
              (v1[m].x + v1[m].y) + (v1[m].z + v1[m].w);
#pragma unroll
    for (int off = 1; off < 64; off <<= 1) s += __shfl_xor(s, off, 64);
    if (lane == 0) {
      float m_ = s * (1.0f / NN);
      mc[b * NN + r0 + w * 4 + m] = m_;
      sMc[w * 4 + m] = m_;
    }
    accR += s;
  }
  if (lane == 0) wsum[w] = accR;
  if (t < 16) {
    float d = Ab[(size_t)(r0 + t) * NN + r0 + t];
    dg[b * NN + r0 + t] = d;
    sDg[t] = d;
  }
  {
    int ic5 = ch >> 2;
    int lrb = (ch & 3) * 16 + w * 4;
    size_t bb = ((size_t)(b * 8 + ic5)) * 8 * 4096;
    int c5a = lane >> 4;
    int Ka = (lane & 15) >> 1;
    int sub = (lane & 1) << 2;
#pragma unroll
    for (int m = 0; m < 4; ++m) {
      int lr = lrb + m;
      int sl = ((Ka ^ (lr & 7)) << 3) + sub;
      union { unsigned short u[4]; uint2 v; } p0, p1;
      p0.u[0] = (unsigned short)f2bf(v0[m].x); p0.u[1] = (unsigned short)f2bf(v0[m].y);
      p0.u[2] = (unsigned short)f2bf(v0[m].z); p0.u[3] = (unsigned short)f2bf(v0[m].w);
      p1.u[0] = (unsigned short)f2bf(v1[m].x); p1.u[1] = (unsigned short)f2bf(v1[m].y);
      p1.u[2] = (unsigned short)f2bf(v1[m].z); p1.u[3] = (unsigned short)f2bf(v1[m].w);
      *(uint2*)(Abf + bb + (size_t)c5a * 4096 + lr * 64 + sl) = p0.v;
      *(uint2*)(Abf + bb + (size_t)(4 + c5a) * 4096 + lr * 64 + sl) = p1.v;
    }
  }
  __syncthreads();

  float c0n = scf[0] * (1.0f / NN);

  if (t < 16) {
    float u = 0.f;
#pragma unroll
    for (int c = 0; c < CI; ++c) u += scf[5 + c] * sXc[t][c];
    float vj = scf[3] * sMc[t] + scf[4] * sDg[t] + u;
    vec[b * NN + r0 + t] = vj;
    sVec[t] = vj;
  } else if (t == 16) {
    pA[b * 32 + ch] = wsum[0] + wsum[1] + wsum[2] + wsum[3];
    float sd = 0.f;
#pragma unroll
    for (int k = 0; k < 16; ++k) sd += sDg[k];
    pD[b * 32 + ch] = sd;
  }
  {
    int ra = lane & 15, kg = lane >> 4, g = lane >> 4;
    const float* wp = W1 + (w * 16 + ra) * XN + kg * 8;
    bf16x8 wf = cvt8(*(const float4*)wp, *(const float4*)(wp + 4));
    const float* xp = &sXc[ra][kg * 8];
    bf16x8 xf = cvt8(*(const float4*)xp, *(const float4*)(xp + 4));
    f32x4 zero = {0.f, 0.f, 0.f, 0.f};
    f32x4 d = __builtin_amdgcn_mfma_f32_16x16x32_bf16(xf, wf, zero, 0, 0, 0);
    union { unsigned short u[4]; uint2 v; } pk;
#pragma unroll
    for (int r = 0; r < 4; ++r) pk.u[r] = (unsigned short)f2bf(d[r] * c0n);
    int o = w * 16 + ra;
    *(uint2*)(Ybf + (((size_t)b * 16 + kb) * 80 + o) * 32 + jbase + g * 4) = pk.v;
  }
  if (t < 16) {
    Ybf[(((size_t)b * 16 + kb) * 80 + 64) * 32 + jbase + t] =
        (unsigned short)f2bf(sMc[t] * c0n);
  } else if (t < 32) {
    Ybf[(((size_t)b * 16 + kb) * 80 + 65) * 32 + jbase + (t - 16)] =
        (unsigned short)f2bf(sDg[t - 16] * c0n);
  } else if (t < 32 + 224) {
    int u2 = t - 32;
    int row = 66 + (u2 >> 4), col = jbase + (u2 & 15);
    Ybf[(((size_t)b * 16 + kb) * 80 + row) * 32 + col] = 0;
  }
  __syncthreads();

  if (t < 32) {
    float s1 = 0.f, s2 = 0.f;
#pragma unroll
    for (int r = 0; r < 16; ++r) {
      float xv = sXc[r][t];
      s1 += xv;
      s2 += sVec[r] * xv;
    }
    pmX[((size_t)b * 32 + ch) * 32 + t] = s1;
    ptC[((size_t)b * 32 + ch) * 32 + t] = s2;
  } else if (t < 35) {
    float s = 0.f;
    if (t == 32) { for (int r = 0; r < 16; ++r) s += sVec[r]; }
    if (t == 33) { for (int r = 0; r < 16; ++r) s += sVec[r] * sMc[r]; }
    if (t == 34) { for (int r = 0; r < 16; ++r) s += sVec[r] * sDg[r]; }
    pS[((size_t)b * 32 + ch) * 3 + (t - 32)] = s;
  }
}

__global__ __launch_bounds__(256) void kW(
    const float* __restrict__ cf, const float* __restrict__ W1,
    const float* __restrict__ W2, const float* __restrict__ pA,
    const float* __restrict__ pD, const float* __restrict__ pmX,
    const float* __restrict__ ptC, const float* __restrict__ pS,
    float* __restrict__ colv, float* __restrict__ sconst) {
  int gb = blockIdx.x, t = threadIdx.x;
  int bb0 = gb * 4;
  __shared__ float sW1[64][69], sW2[64][69];
  __shared__ float mXs[4][33], tCs[4][33];
  __shared__ float scal[4][6];
  __shared__ float scf[69];
  if (t < 69) scf[t] = cf[t];
  for (int idx = t; idx < 64 * XN; idx += 256) {
    int r = idx / XN, c = idx - r * XN;
    sW1[r][c] = W1[idx];
    sW2[r][c] = W2[idx];
  }
  if (t < 128) {
    int bb = t >> 5, c = t & 31, b = bb0 + bb;
    float s1 = 0.f, s2 = 0.f;
#pragma unroll
    for (int k = 0; k < 32; ++k) {
      s1 += pmX[((size_t)b * 32 + k) * 32 + c];
      s2 += ptC[((size_t)b * 32 + k) * 32 + c];
    }
    mXs[bb][c] = s1 * (1.0f / NN);
    tCs[bb][c] = s2;
  } else if (t < 132) {
    int bb = t - 128, b = bb0 + bb;
    float sA = 0.f, sD = 0.f;
#pragma unroll
    for (int k = 0; k < 32; ++k) { sA += pA[b * 32 + k]; sD += pD[b * 32 + k]; }
    scal[bb][0] = sD * (1.0f / NN);
    scal[bb][1] = sA * (1.0f / ((float)NN * (float)NN));
  } else if (t < 136) {
    int bb = t - 132, b = bb0 + bb;
    float s1 = 0.f, s2 = 0.f, s3 = 0.f;
#pragma unroll
    for (int k = 0; k < 32; ++k) {
      s1 += pS[((size_t)b * 32 + k) * 3 + 0];
      s2 += pS[((size_t)b * 32 + k) * 3 + 1];
      s3 += pS[((size_t)b * 32 + k) * 3 + 2];
    }
    scal[bb][2] = s1; scal[bb][3] = s2; scal[bb][4] = s3;
  }
  __syncthreads();
  if (t < 4) {
    float s7 = 0.f;
#pragma unroll
    for (int c = 0; c < CI; ++c) s7 += scf[5 + CI + c] * mXs[t][c];
    sconst[bb0 + t] = scf[1] * scal[t][1] + scf[2] * scal[t][0] + s7;
  }
  {
    int bb = t >> 6, o = t & 63, b = bb0 + bb;
    float w1mX = 0.f, a1 = 0.f, a2 = 0.f, wt = 0.f;
#pragma unroll
    for (int c = 0; c < CI; ++c) {
      float m = mXs[bb][c];
      w1mX += sW1[o][c] * m;
      a1 += sW1[o][CI + c] * m;
      a2 += sW2[o][CI + c] * m;
      wt += sW1[o][c] * tCs[bb][c];
    }
    float smd = scal[bb][0], sma = scal[bb][1];
    a1 += sW1[o][66] * smd + sW1[o][67] * sma;
    a2 += sW2[o][66] * smd + sW2[o][67] * sma;
    float we0 = sW1[o][64], we1 = sW1[o][65];
    float S1n = w1mX + a1 + we0 * sma + we1 * smd;
    float SVn = (wt + a1 * scal[bb][2] + we0 * scal[bb][3] + we1 * scal[bb][4]) * (1.0f / NN);
    float4 cva = make_float4(S1n, a2 + SVn, sW2[o][64] + scf[0] * a1, sW2[o][65]);
    float4 cvb = make_float4(we0, we1, 0.f, 0.f);
    *(float4*)&colv[((size_t)b * CO + o) * 8] = cva;
    *(float4*)&colv[((size_t)b * CO + o) * 8 + 4] = cvb;
  }
}

__global__ __launch_bounds__(512, 2) void k5_mfma(
    const unsigned short* __restrict__ Abf, const unsigned short* __restrict__ Ybf,
    const float* __restrict__ X, const float* __restrict__ W2,
    const float* __restrict__ vec, const float* __restrict__ mc,
    const float* __restrict__ dg, const float* __restrict__ colv,
    const float* __restrict__ sconst, float* __restrict__ out) {
  int ic = blockIdx.x, b = blockIdx.y;
  int t = threadIdx.x, w = t >> 6, lane = t & 63;
  int rg = w >> 1, oc = w & 1;
  int ra = lane & 15, kg = lane >> 4, g = lane >> 4;
  int i0 = ic * 64;
  int wr0 = rg * 16;
  __shared__ unsigned short sA[2][4096];
  __shared__ unsigned short sB[2][160 * 40];
  __shared__ float sGm[64], sGd[64];

  const unsigned short* Asrc = Abf + ((size_t)(b * 8 + ic)) * 8 * 4096;
  const unsigned short* Yb = Ybf + (size_t)b * 16 * 80 * 32;

  int b1_row = t >> 2, b1_sub = t & 3;
  int b2_row = 128 + (t >> 2), b2_sub = t & 3;
  bool hasb2 = (t < 128);

  {
    uint4 av = *(const uint4*)(Asrc + t * 8);
    *(uint4*)&sA[0][t * 8] = av;
    uint4 v1 = *(const uint4*)(Yb + b1_row * 32 + b1_sub * 8);
    *(uint4*)&sB[0][b1_row * 40 + b1_sub * 8] = v1;
    if (hasb2) {
      uint4 v2 = *(const uint4*)(Yb + b2_row * 32 + b2_sub * 8);
      *(uint4*)&sB[0][b2_row * 40 + b2_sub * 8] = v2;
    }
  }
  uint4 rCa = *(const uint4*)(Asrc + 4096 + t * 8);
  uint4 rCb1 = *(const uint4*)(Yb + 160 * 32 + b1_row * 32 + b1_sub * 8);
  uint4 rCb2;
  if (hasb2) rCb2 = *(const uint4*)(Yb + 160 * 32 + b2_row * 32 + b2_sub * 8);
  __syncthreads();

  f32x4 acc[2] = {{0.f, 0.f, 0.f, 0.f}, {0.f, 0.f, 0.f, 0.f}};
  f32x4 acc4 = {0.f, 0.f, 0.f, 0.f};
  int arow = wr0 + ra;
  int abase = arow * 64;
  int aswz = arow & 7;

  for (int c = 0; c < 8; ++c) {
    int cur = c & 1;
    uint4 rNa, rNb1, rNb2;
    if (c < 6) {
      rNa = *(const uint4*)(Asrc + (size_t)(c + 2) * 4096 + t * 8);
      const unsigned short* nsrc = Yb + (size_t)(c + 2) * 160 * 32;
      rNb1 = *(const uint4*)(nsrc + b1_row * 32 + b1_sub * 8);
      if (hasb2) rNb2 = *(const uint4*)(nsrc + b2_row * 32 + b2_sub * 8);
    }
    __builtin_amdgcn_sched_barrier(0);
#pragma unroll
    for (int kbl = 0; kbl < 2; ++kbl) {
      bf16x8 af = *(const bf16x8*)&sA[cur][abase + (((kbl * 4 + kg) ^ aswz) << 3)];
#pragma unroll
      for (int to = 0; to < 2; ++to) {
        int grow = kbl * 80 + oc * 32 + to * 16 + ra;
        bf16x8 bf = *(const bf16x8*)&sB[cur][grow * 40 + kg * 8];
        acc[to] = __builtin_amdgcn_mfma_f32_16x16x32_bf16(af, bf, acc[to], 0, 0, 0);
      }
      if (oc == 0) {
        bf16x8 bf4 = *(const bf16x8*)&sB[cur][(kbl * 80 + 64 + ra) * 40 + kg * 8];
        acc4 = __builtin_amdgcn_mfma_f32_16x16x32_bf16(af, bf4, acc4, 0, 0, 0);
      }
    }
    if (c < 7) {
      *(uint4*)&sA[cur ^ 1][t * 8] = rCa;
      *(uint4*)&sB[cur ^ 1][b1_row * 40 + b1_sub * 8] = rCb1;
      if (hasb2) *(uint4*)&sB[cur ^ 1][b2_row * 40 + b2_sub * 8] = rCb2;
      rCa = rNa; rCb1 = rNb1;
      if (hasb2) rCb2 = rNb2;
    }
    __syncthreads();
  }

  {
    const float* xp = X + (size_t)(b * NN + i0 + wr0 + ra) * CI + kg * 8;
    bf16x8 xf = cvt8(*(const float4*)xp, *(const float4*)(xp + 4));
#pragma unroll
    for (int to = 0; to < 2; ++to) {
      const float* wp = W2 + (size_t)(oc * 32 + to * 16 + ra) * XN + kg * 8;
      bf16x8 wf = cvt8(*(const float4*)wp, *(const float4*)(wp + 4));
      acc[to] = __builtin_amdgcn_mfma_f32_16x16x32_bf16(xf, wf, acc[to], 0, 0, 0);
    }
  }

  if (oc == 0 && ra < 2) {
#pragma unroll
    for (int r = 0; r < 4; ++r) {
      if (ra == 0) sGm[wr0 + g * 4 + r] = acc4[r];
      else         sGd[wr0 + g * 4 + r] = acc4[r];
    }
  }
  __syncthreads();

  float4 v4 = *(const float4*)&vec[b * NN + i0 + wr0 + g * 4];
  float4 m4 = *(const float4*)&mc[b * NN + i0 + wr0 + g * 4];
  float4 d4 = *(const float4*)&dg[b * NN + i0 + wr0 + g * 4];
  float sc = sconst[b];
  float vp[4] = {v4.x + sc, v4.y + sc, v4.z + sc, v4.w + sc};
  float mr[4] = {m4.x, m4.y, m4.z, m4.w};
  float dr[4] = {d4.x, d4.y, d4.z, d4.w};
  float Gm[4], Gd[4];
#pragma unroll
  for (int r = 0; r < 4; ++r) {
    int row = wr0 + g * 4 + r;
    Gm[r] = sGm[row];
    Gd[r] = sGd[row];
  }

#pragma unroll
  for (int to = 0; to < 2; ++to) {
    int o = oc * 32 + to * 16 + ra;
    float4 cva = *(const float4*)&colv[((size_t)b * CO + o) * 8];
    float4 cvb = *(const float4*)&colv[((size_t)b * CO + o) * 8 + 4];
#pragma unroll
    for (int r = 0; r < 4; ++r) {
      float val = acc[to][r] + vp[r] * cva.x + cva.y + mr[r] * cva.z +
                  dr[r] * cva.w + Gm[r] * cvb.x + Gd[r] * cvb.y;
      out[((size_t)(b * NN + i0 + wr0 + g * 4 + r)) * CO + o] = val;
    }
  }
}

extern "C" void kernel_launch(void* const* d_in, const int* in_sizes, int n_in,
                              void* d_out, int out_size, void* d_ws, size_t ws_size,
                              hipStream_t stream) {
  const float* A = (const float*)d_in[0];
  const float* X = (const float*)d_in[1];
  const float* cf = (const float*)d_in[2];
  const float* W1 = (const float*)d_in[3];
  const float* W2 = (const float*)d_in[4];
  float* out = (float*)d_out;

  // --- try cooperative single-pass (coop buffers carved from ws base) ---
  {
    float* p = (float*)d_ws;
    float* cpA = p;   p += NB * 4;
    float* cpD = p;   p += NB * 4;
    float* cpS = p;   p += NB * 4 * 3;
    float* cpmX = p;  p += NB * 4 * 32;
    float* cptC = p;  p += NB * 4 * 32;
    unsigned short* cYbf = (unsigned short*)p;

    void* kargs[] = {(void*)&A, (void*)&X, (void*)&cf, (void*)&W1, (void*)&W2,
                     (void*)&cpA, (void*)&cpD, (void*)&cpS, (void*)&cpmX,
                     (void*)&cptC, (void*)&cYbf, (void*)&out};
    hipError_t err = hipLaunchCooperativeKernel((void*)kmain, dim3(4, NB),
                                                dim3(512), kargs, 0, stream);
    if (err == hipSuccess) return;
    (void)hipGetLastError();  // clear sticky error; fall through to fallback
  }

  // --- fallback: proven 3-kernel path (45.9 µs) ---
  float* p = (float*)d_ws;
  float* mc = p;      p += NB * NN;
  float* dg = p;      p += NB * NN;
  float* vec = p;     p += NB * NN;
  float* pA = p;      p += NB * 32;
  float* pD = p;      p += NB * 32;
  float* pmX = p;     p += NB * 32 * 32;
  float* ptC = p;     p += NB * 32 * 32;
  float* pS = p;      p += NB * 32 * 3;
  float* colv = p;    p += NB * CO * 8;
  float* sconst = p;  p += NB;
  unsigned short* Ybf = (unsigned short*)p;
  unsigned short* Abf = Ybf + (size_t)NB * 16 * 80 * 32;

  k1x<<<dim3(NB, 32), 256, 0, stream>>>(A, X, cf, W1, mc, dg, vec,
                                        pA, pD, pmX, ptC, pS, Ybf, Abf);
  kW<<<16, 256, 0, stream>>>(cf, W1, W2, pA, pD, pmX, ptC, pS, colv, sconst);
  k5_mfma<<<dim3(8, NB), 512, 0, stream>>>(Abf, Ybf, X, W2, vec, mc, dg,
                                           colv, sconst, out);
}

// Round 26
// 46.045 us; speedup vs baseline: 3.5683x; 3.5683x over previous
//
#include <hip/hip_runtime.h>
#include <hip/hip_bf16.h>

#define NB 64
#define NN 512
#define CI 32
#define CO 64
#define XN 68
// Ybf layout: [b][kb=0..15][row=0..79][32], bf16, pre-scaled by c0/n.
// Abf layout: [b][ic=0..7][c=0..7][4096], bf16(A), fragment-linear XOR-swizzled:
//   element (local row r 0..63, kk 0..63) at r*64 + (((kk>>3) ^ (r&7))<<3) + (kk&7).

typedef __attribute__((ext_vector_type(8))) short bf16x8;
typedef __attribute__((ext_vector_type(4))) float f32x4;

__device__ inline short f2bf(float f) {
  union { __hip_bfloat16 h; unsigned short u; } cv;
  cv.h = __float2bfloat16(f);
  return (short)cv.u;
}

__device__ inline bf16x8 cvt8(float4 a, float4 b) {
  bf16x8 r;
  r[0] = f2bf(a.x); r[1] = f2bf(a.y); r[2] = f2bf(a.z); r[3] = f2bf(a.w);
  r[4] = f2bf(b.x); r[5] = f2bf(b.y); r[6] = f2bf(b.z); r[7] = f2bf(b.w);
  return r;
}

// ---------------- K1X: A row stats + X stats + Ybf chunk + Abf. grid (NB,32) ----------------
__global__ __launch_bounds__(256) void k1x(
    const float* __restrict__ A, const float* __restrict__ X,
    const float* __restrict__ cf, const float* __restrict__ W1,
    float* __restrict__ mc, float* __restrict__ dg, float* __restrict__ vec,
    float* __restrict__ pA, float* __restrict__ pD,
    float* __restrict__ pmX, float* __restrict__ ptC, float* __restrict__ pS,
    unsigned short* __restrict__ Ybf, unsigned short* __restrict__ Abf) {
  int b = blockIdx.x, ch = blockIdx.y;
  int t = threadIdx.x, w = t >> 6, lane = t & 63;
  int r0 = ch * 16;
  int kb = r0 >> 5, jbase = r0 & 16;
  const float* Ab = A + (size_t)b * NN * NN;
  __shared__ float sXc[16][33];
  __shared__ float scf[69];
  __shared__ float sMc[16], sDg[16], sVec[16], wsum[4];

  if (t < 69) scf[t] = cf[t];
  {  // stage X chunk: 16 rows x 32 cols
    int j = t >> 4, c = (t & 15) * 2;
    float2 xv = *(const float2*)(X + ((size_t)b * NN + r0 + j) * CI + c);
    sXc[j][c] = xv.x; sXc[j][c + 1] = xv.y;
  }
  float4 v0[4], v1[4];
#pragma unroll
  for (int m = 0; m < 4; ++m) {
    const float* rp = Ab + (size_t)(r0 + w * 4 + m) * NN;
    v0[m] = *(const float4*)(rp + lane * 4);
    v1[m] = *(const float4*)(rp + 256 + lane * 4);
  }
  float accR = 0.f;
#pragma unroll
  for (int m = 0; m < 4; ++m) {
    float s = (v0[m].x + v0[m].y) + (v0[m].z + v0[m].w) +
              (v1[m].x + v1[m].y) + (v1[m].z + v1[m].w);
#pragma unroll
    for (int off = 1; off < 64; off <<= 1) s += __shfl_xor(s, off, 64);
    if (lane == 0) {
      float m_ = s * (1.0f / NN);
      mc[b * NN + r0 + w * 4 + m] = m_;
      sMc[w * 4 + m] = m_;
    }
    accR += s;
  }
  if (lane == 0) wsum[w] = accR;
  if (t < 16) {
    float d = Ab[(size_t)(r0 + t) * NN + r0 + t];
    dg[b * NN + r0 + t] = d;
    sDg[t] = d;
  }

  {  // Abf: bf16(A) in k5-fragment-linear order (local rows within 64-row tile)
    int ic5 = ch >> 2;
    int lrb = (ch & 3) * 16 + w * 4;
    size_t bb = ((size_t)(b * 8 + ic5)) * 8 * 4096;
    int c5a = lane >> 4;                 // chunk for cols 0..255
    int Ka = (lane & 15) >> 1;           // 8-elem slot
    int sub = (lane & 1) << 2;           // element offset within slot
#pragma unroll
    for (int m = 0; m < 4; ++m) {
      int lr = lrb + m;
      int sl = ((Ka ^ (lr & 7)) << 3) + sub;
      union { unsigned short u[4]; uint2 v; } p0, p1;
      p0.u[0] = (unsigned short)f2bf(v0[m].x); p0.u[1] = (unsigned short)f2bf(v0[m].y);
      p0.u[2] = (unsigned short)f2bf(v0[m].z); p0.u[3] = (unsigned short)f2bf(v0[m].w);
      p1.u[0] = (unsigned short)f2bf(v1[m].x); p1.u[1] = (unsigned short)f2bf(v1[m].y);
      p1.u[2] = (unsigned short)f2bf(v1[m].z); p1.u[3] = (unsigned short)f2bf(v1[m].w);
      *(uint2*)(Abf + bb + (size_t)c5a * 4096 + lr * 64 + sl) = p0.v;
      *(uint2*)(Abf + bb + (size_t)(4 + c5a) * 4096 + lr * 64 + sl) = p1.v;
    }
  }
  __syncthreads();  // sXc, sMc, sDg, wsum, scf ready

  float c0n = scf[0] * (1.0f / NN);

  if (t < 16) {  // vec for this chunk's 16 rows
    float u = 0.f;
#pragma unroll
    for (int c = 0; c < CI; ++c) u += scf[5 + c] * sXc[t][c];
    float vj = scf[3] * sMc[t] + scf[4] * sDg[t] + u;
    vec[b * NN + r0 + t] = vj;
    sVec[t] = vj;
  } else if (t == 16) {
    pA[b * 32 + ch] = wsum[0] + wsum[1] + wsum[2] + wsum[3];
    float sd = 0.f;
#pragma unroll
    for (int k = 0; k < 16; ++k) sd += sDg[k];
    pD[b * 32 + ch] = sd;
  }

  {  // Y chunk via MFMA (scaled by c0/n): wave w -> rows o = w*16..+15, cols r0..+15
    int ra = lane & 15, kg = lane >> 4, g = lane >> 4;
    const float* wp = W1 + (w * 16 + ra) * XN + kg * 8;
    bf16x8 wf = cvt8(*(const float4*)wp, *(const float4*)(wp + 4));
    const float* xp = &sXc[ra][kg * 8];
    bf16x8 xf = cvt8(*(const float4*)xp, *(const float4*)(xp + 4));
    f32x4 zero = {0.f, 0.f, 0.f, 0.f};
    f32x4 d = __builtin_amdgcn_mfma_f32_16x16x32_bf16(xf, wf, zero, 0, 0, 0);
    union { unsigned short u[4]; uint2 v; } pk;
#pragma unroll
    for (int r = 0; r < 4; ++r) pk.u[r] = (unsigned short)f2bf(d[r] * c0n);
    int o = w * 16 + ra;
    *(uint2*)(Ybf + (((size_t)b * 16 + kb) * 80 + o) * 32 + jbase + g * 4) = pk.v;
  }
  // Ybf rows 64 (c0n*mc), 65 (c0n*dg) + zero pads 66..79, this chunk's 16 cols
  if (t < 16) {
    Ybf[(((size_t)b * 16 + kb) * 80 + 64) * 32 + jbase + t] =
        (unsigned short)f2bf(sMc[t] * c0n);
  } else if (t < 32) {
    Ybf[(((size_t)b * 16 + kb) * 80 + 65) * 32 + jbase + (t - 16)] =
        (unsigned short)f2bf(sDg[t - 16] * c0n);
  } else if (t < 32 + 224) {
    int u2 = t - 32;
    int row = 66 + (u2 >> 4), col = jbase + (u2 & 15);
    Ybf[(((size_t)b * 16 + kb) * 80 + row) * 32 + col] = 0;
  }
  __syncthreads();  // sVec ready

  if (t < 32) {  // column partials over this chunk
    float s1 = 0.f, s2 = 0.f;
#pragma unroll
    for (int r = 0; r < 16; ++r) {
      float xv = sXc[r][t];
      s1 += xv;
      s2 += sVec[r] * xv;
    }
    pmX[((size_t)b * 32 + ch) * 32 + t] = s1;
    ptC[((size_t)b * 32 + ch) * 32 + t] = s2;
  } else if (t < 35) {
    float s = 0.f;
    if (t == 32) { for (int r = 0; r < 16; ++r) s += sVec[r]; }
    if (t == 33) { for (int r = 0; r < 16; ++r) s += sVec[r] * sMc[r]; }
    if (t == 34) { for (int r = 0; r < 16; ++r) s += sVec[r] * sDg[r]; }
    pS[((size_t)b * 32 + ch) * 3 + (t - 32)] = s;
  }
}

// ---------------- KW: finalize stats -> colv, sconst. grid (16) ----------------
__global__ __launch_bounds__(256) void kW(
    const float* __restrict__ cf, const float* __restrict__ W1,
    const float* __restrict__ W2, const float* __restrict__ pA,
    const float* __restrict__ pD, const float* __restrict__ pmX,
    const float* __restrict__ ptC, const float* __restrict__ pS,
    float* __restrict__ colv, float* __restrict__ sconst) {
  int gb = blockIdx.x, t = threadIdx.x;
  int bb0 = gb * 4;
  __shared__ float sW1[64][69], sW2[64][69];
  __shared__ float mXs[4][33], tCs[4][33];
  __shared__ float scal[4][6];
  __shared__ float scf[69];
  if (t < 69) scf[t] = cf[t];
  for (int idx = t; idx < 64 * XN; idx += 256) {
    int r = idx / XN, c = idx - r * XN;
    sW1[r][c] = W1[idx];
    sW2[r][c] = W2[idx];
  }
  if (t < 128) {
    int bb = t >> 5, c = t & 31, b = bb0 + bb;
    float s1 = 0.f, s2 = 0.f;
#pragma unroll
    for (int k = 0; k < 32; ++k) {
      s1 += pmX[((size_t)b * 32 + k) * 32 + c];
      s2 += ptC[((size_t)b * 32 + k) * 32 + c];
    }
    mXs[bb][c] = s1 * (1.0f / NN);
    tCs[bb][c] = s2;
  } else if (t < 132) {
    int bb = t - 128, b = bb0 + bb;
    float sA = 0.f, sD = 0.f;
#pragma unroll
    for (int k = 0; k < 32; ++k) { sA += pA[b * 32 + k]; sD += pD[b * 32 + k]; }
    scal[bb][0] = sD * (1.0f / NN);
    scal[bb][1] = sA * (1.0f / ((float)NN * (float)NN));
  } else if (t < 136) {
    int bb = t - 132, b = bb0 + bb;
    float s1 = 0.f, s2 = 0.f, s3 = 0.f;
#pragma unroll
    for (int k = 0; k < 32; ++k) {
      s1 += pS[((size_t)b * 32 + k) * 3 + 0];
      s2 += pS[((size_t)b * 32 + k) * 3 + 1];
      s3 += pS[((size_t)b * 32 + k) * 3 + 2];
    }
    scal[bb][2] = s1; scal[bb][3] = s2; scal[bb][4] = s3;
  }
  __syncthreads();
  if (t < 4) {
    float s7 = 0.f;
#pragma unroll
    for (int c = 0; c < CI; ++c) s7 += scf[5 + CI + c] * mXs[t][c];
    sconst[bb0 + t] = scf[1] * scal[t][1] + scf[2] * scal[t][0] + s7;
  }
  {
    int bb = t >> 6, o = t & 63, b = bb0 + bb;
    float w1mX = 0.f, a1 = 0.f, a2 = 0.f, wt = 0.f;
#pragma unroll
    for (int c = 0; c < CI; ++c) {
      float m = mXs[bb][c];
      w1mX += sW1[o][c] * m;
      a1 += sW1[o][CI + c] * m;
      a2 += sW2[o][CI + c] * m;
      wt += sW1[o][c] * tCs[bb][c];
    }
    float smd = scal[bb][0], sma = scal[bb][1];
    a1 += sW1[o][66] * smd + sW1[o][67] * sma;
    a2 += sW2[o][66] * smd + sW2[o][67] * sma;
    float we0 = sW1[o][64], we1 = sW1[o][65];
    float S1n = w1mX + a1 + we0 * sma + we1 * smd;
    float SVn = (wt + a1 * scal[bb][2] + we0 * scal[bb][3] + we1 * scal[bb][4]) * (1.0f / NN);
    float4 cva = make_float4(S1n, a2 + SVn, sW2[o][64] + scf[0] * a1, sW2[o][65]);
    float4 cvb = make_float4(we0, we1, 0.f, 0.f);
    *(float4*)&colv[((size_t)b * CO + o) * 8] = cva;
    *(float4*)&colv[((size_t)b * CO + o) * 8 + 4] = cvb;
  }
}

// ---------------- K5 v4d: A from bf16 Abf (L3-hot, linear copy), B LDS-staged ----------------
// grid (8, NB), 512 threads = 8 waves = 4 row-groups (rg) x 2 col-halves (oc).
// Depth-2 register prefetch (loads span a full chunk iteration before their ds_write).
__global__ __launch_bounds__(512, 2) void k5_mfma(
    const unsigned short* __restrict__ Abf, const unsigned short* __restrict__ Ybf,
    const float* __restrict__ X, const float* __restrict__ W2,
    const float* __restrict__ vec, const float* __restrict__ mc,
    const float* __restrict__ dg, const float* __restrict__ colv,
    const float* __restrict__ sconst, float* __restrict__ out) {
  int ic = blockIdx.x, b = blockIdx.y;
  int t = threadIdx.x, w = t >> 6, lane = t & 63;
  int rg = w >> 1, oc = w & 1;
  int ra = lane & 15, kg = lane >> 4, g = lane >> 4;
  int i0 = ic * 64;
  int wr0 = rg * 16;
  __shared__ unsigned short sA[2][4096];        // 8KB/buf, fragment-linear (pre-swizzled)
  __shared__ unsigned short sB[2][160 * 40];    // B rows @ 80B stride (2-way only)
  __shared__ float sGm[64], sGd[64];

  const unsigned short* Asrc = Abf + ((size_t)(b * 8 + ic)) * 8 * 4096;
  const unsigned short* Yb = Ybf + (size_t)b * 16 * 80 * 32;

  // B staging: chunk = 160 linear rows of 32 ushort (two kb panels, contiguous).
  int b1_row = t >> 2, b1_sub = t & 3;
  int b2_row = 128 + (t >> 2), b2_sub = t & 3;
  bool hasb2 = (t < 128);

  // prologue: chunk 0 direct to LDS; chunk 1 into regC (stays in flight)
  {
    uint4 av = *(const uint4*)(Asrc + t * 8);
    *(uint4*)&sA[0][t * 8] = av;
    uint4 v1 = *(const uint4*)(Yb + b1_row * 32 + b1_sub * 8);
    *(uint4*)&sB[0][b1_row * 40 + b1_sub * 8] = v1;
    if (hasb2) {
      uint4 v2 = *(const uint4*)(Yb + b2_row * 32 + b2_sub * 8);
      *(uint4*)&sB[0][b2_row * 40 + b2_sub * 8] = v2;
    }
  }
  uint4 rCa = *(const uint4*)(Asrc + 4096 + t * 8);
  uint4 rCb1 = *(const uint4*)(Yb + 160 * 32 + b1_row * 32 + b1_sub * 8);
  uint4 rCb2;
  if (hasb2) rCb2 = *(const uint4*)(Yb + 160 * 32 + b2_row * 32 + b2_sub * 8);
  __syncthreads();

  f32x4 acc[2] = {{0.f, 0.f, 0.f, 0.f}, {0.f, 0.f, 0.f, 0.f}};
  f32x4 acc4 = {0.f, 0.f, 0.f, 0.f};
  int arow = wr0 + ra;
  int abase = arow * 64;
  int aswz = arow & 7;

  for (int c = 0; c < 8; ++c) {
    int cur = c & 1;
    uint4 rNa, rNb1, rNb2;
    if (c < 6) {  // far prefetch: chunk c+2
      rNa = *(const uint4*)(Asrc + (size_t)(c + 2) * 4096 + t * 8);
      const unsigned short* nsrc = Yb + (size_t)(c + 2) * 160 * 32;
      rNb1 = *(const uint4*)(nsrc + b1_row * 32 + b1_sub * 8);
      if (hasb2) rNb2 = *(const uint4*)(nsrc + b2_row * 32 + b2_sub * 8);
    }
    __builtin_amdgcn_sched_barrier(0);  // keep prefetch issue above the MFMAs
#pragma unroll
    for (int kbl = 0; kbl < 2; ++kbl) {
      bf16x8 af = *(const bf16x8*)&sA[cur][abase + (((kbl * 4 + kg) ^ aswz) << 3)];
#pragma unroll
      for (int to = 0; to < 2; ++to) {
        int grow = kbl * 80 + oc * 32 + to * 16 + ra;
        bf16x8 bf = *(const bf16x8*)&sB[cur][grow * 40 + kg * 8];
        acc[to] = __builtin_amdgcn_mfma_f32_16x16x32_bf16(af, bf, acc[to], 0, 0, 0);
      }
      if (oc == 0) {
        bf16x8 bf4 = *(const bf16x8*)&sB[cur][(kbl * 80 + 64 + ra) * 40 + kg * 8];
        acc4 = __builtin_amdgcn_mfma_f32_16x16x32_bf16(af, bf4, acc4, 0, 0, 0);
      }
    }
    if (c < 7) {  // write chunk c+1 (regC, issued one full iteration ago)
      *(uint4*)&sA[cur ^ 1][t * 8] = rCa;
      *(uint4*)&sB[cur ^ 1][b1_row * 40 + b1_sub * 8] = rCb1;
      if (hasb2) *(uint4*)&sB[cur ^ 1][b2_row * 40 + b2_sub * 8] = rCb2;
      rCa = rNa; rCb1 = rNb1;
      if (hasb2) rCb2 = rNb2;
    }
    __syncthreads();
  }

  {  // fused X*W2c k-step (unscaled)
    const float* xp = X + (size_t)(b * NN + i0 + wr0 + ra) * CI + kg * 8;
    bf16x8 xf = cvt8(*(const float4*)xp, *(const float4*)(xp + 4));
#pragma unroll
    for (int to = 0; to < 2; ++to) {
      const float* wp = W2 + (size_t)(oc * 32 + to * 16 + ra) * XN + kg * 8;
      bf16x8 wf = cvt8(*(const float4*)wp, *(const float4*)(wp + 4));
      acc[to] = __builtin_amdgcn_mfma_f32_16x16x32_bf16(xf, wf, acc[to], 0, 0, 0);
    }
  }

  // share Gm/Gd (oc==0 waves; acc4 col 0 -> Gm, col 1 -> Gd)
  if (oc == 0 && ra < 2) {
#pragma unroll
    for (int r = 0; r < 4; ++r) {
      if (ra == 0) sGm[wr0 + g * 4 + r] = acc4[r];
      else         sGd[wr0 + g * 4 + r] = acc4[r];
    }
  }
  __syncthreads();

  // epilogue
  float4 v4 = *(const float4*)&vec[b * NN + i0 + wr0 + g * 4];
  float4 m4 = *(const float4*)&mc[b * NN + i0 + wr0 + g * 4];
  float4 d4 = *(const float4*)&dg[b * NN + i0 + wr0 + g * 4];
  float sc = sconst[b];
  float vp[4] = {v4.x + sc, v4.y + sc, v4.z + sc, v4.w + sc};
  float mr[4] = {m4.x, m4.y, m4.z, m4.w};
  float dr[4] = {d4.x, d4.y, d4.z, d4.w};
  float Gm[4], Gd[4];
#pragma unroll
  for (int r = 0; r < 4; ++r) {
    int row = wr0 + g * 4 + r;
    Gm[r] = sGm[row];
    Gd[r] = sGd[row];
  }

#pragma unroll
  for (int to = 0; to < 2; ++to) {
    int o = oc * 32 + to * 16 + ra;
    float4 cva = *(const float4*)&colv[((size_t)b * CO + o) * 8];
    float4 cvb = *(const float4*)&colv[((size_t)b * CO + o) * 8 + 4];
#pragma unroll
    for (int r = 0; r < 4; ++r) {
      float val = acc[to][r] + vp[r] * cva.x + cva.y + mr[r] * cva.z +
                  dr[r] * cva.w + Gm[r] * cvb.x + Gd[r] * cvb.y;
      out[((size_t)(b * NN + i0 + wr0 + g * 4 + r)) * CO + o] = val;
    }
  }
}

extern "C" void kernel_launch(void* const* d_in, const int* in_sizes, int n_in,
                              void* d_out, int out_size, void* d_ws, size_t ws_size,
                              hipStream_t stream) {
  const float* A = (const float*)d_in[0];
  const float* X = (const float*)d_in[1];
  const float* cf = (const float*)d_in[2];
  const float* W1 = (const float*)d_in[3];
  const float* W2 = (const float*)d_in[4];
  float* out = (float*)d_out;

  float* p = (float*)d_ws;
  float* mc = p;      p += NB * NN;
  float* dg = p;      p += NB * NN;
  float* vec = p;     p += NB * NN;
  float* pA = p;      p += NB * 32;
  float* pD = p;      p += NB * 32;
  float* pmX = p;     p += NB * 32 * 32;
  float* ptC = p;     p += NB * 32 * 32;
  float* pS = p;      p += NB * 32 * 3;
  float* colv = p;    p += NB * CO * 8;
  float* sconst = p;  p += NB;
  unsigned short* Ybf = (unsigned short*)p;
  unsigned short* Abf = Ybf + (size_t)NB * 16 * 80 * 32;

  k1x<<<dim3(NB, 32), 256, 0, stream>>>(A, X, cf, W1, mc, dg, vec,
                                        pA, pD, pmX, ptC, pS, Ybf, Abf);
  kW<<<16, 256, 0, stream>>>(cf, W1, W2, pA, pD, pmX, ptC, pS, colv, sconst);
  k5_mfma<<<dim3(8, NB), 512, 0, stream>>>(Abf, Ybf, X, W2, vec, mc, dg,
                                           colv, sconst, out);
}